// Round 4
// baseline (87.363 us; speedup 1.0000x reference)
//
#include <hip/hip_runtime.h>

typedef float  float4_t __attribute__((ext_vector_type(4)));
typedef int    int4_t   __attribute__((ext_vector_type(4)));

#define UNROLL 4

// Block-partitioned, 4 vec4 units per thread, region-strided:
//   blocks [0, blocksV)          : vals region  (new_vals = keep ? vals/kr : 0)
//   blocks [blocksV, blocksV+I)  : idx region   (out[E+j] = (float)idxs[j])
// Strided unit indices (i + k*stride) keep every instruction's 64-lane access
// contiguous (1 KiB segments); 4-8 independent loads issued per thread before
// any wait -> 4x fewer workgroups, 4x more bytes in flight per wave.
__global__ void SpAdjDropEdge_48541720379660_kernel(
    const float* __restrict__ vals,
    const int*   __restrict__ idxs,
    const float* __restrict__ rand_u,
    const float* __restrict__ keep_rate_p,
    float*       __restrict__ out,
    int nv4, int ni4, int blocksV)
{
    if ((int)blockIdx.x < blocksV) {
        const int t      = blockIdx.x * blockDim.x + threadIdx.x;
        const int stride = blocksV * blockDim.x;
        const float kr   = keep_rate_p[0];

        int  idx_[UNROLL];
        bool ok_[UNROLL];
        float4_t v_[UNROLL], r_[UNROLL];
#pragma unroll
        for (int k = 0; k < UNROLL; ++k) {
            idx_[k] = t + k * stride;
            ok_[k]  = idx_[k] < nv4;
        }
#pragma unroll
        for (int k = 0; k < UNROLL; ++k)
            if (ok_[k]) v_[k] = reinterpret_cast<const float4_t*>(vals)[idx_[k]];
#pragma unroll
        for (int k = 0; k < UNROLL; ++k)
            if (ok_[k]) r_[k] = reinterpret_cast<const float4_t*>(rand_u)[idx_[k]];
#pragma unroll
        for (int k = 0; k < UNROLL; ++k) {
            if (ok_[k]) {
                float4_t o;
#pragma unroll
                for (int j = 0; j < 4; ++j) {
                    bool keep = (floorf(r_[k][j] + kr) != 0.0f);
                    o[j] = keep ? (v_[k][j] / kr) : 0.0f;
                }
                reinterpret_cast<float4_t*>(out)[idx_[k]] = o;
            }
        }
    } else {
        const int t      = (blockIdx.x - blocksV) * blockDim.x + threadIdx.x;
        const int stride = (gridDim.x - blocksV) * blockDim.x;
        float* outi = out + (size_t)nv4 * 4;

        int  idx_[UNROLL];
        bool ok_[UNROLL];
        int4_t a_[UNROLL];
#pragma unroll
        for (int k = 0; k < UNROLL; ++k) {
            idx_[k] = t + k * stride;
            ok_[k]  = idx_[k] < ni4;
        }
#pragma unroll
        for (int k = 0; k < UNROLL; ++k)
            if (ok_[k]) a_[k] = reinterpret_cast<const int4_t*>(idxs)[idx_[k]];
#pragma unroll
        for (int k = 0; k < UNROLL; ++k) {
            if (ok_[k]) {
                float4_t o;
#pragma unroll
                for (int j = 0; j < 4; ++j)
                    o[j] = (float)a_[k][j];   // node ids < 2^24 -> exact in f32
                reinterpret_cast<float4_t*>(outi)[idx_[k]] = o;
            }
        }
    }
}

extern "C" void kernel_launch(void* const* d_in, const int* in_sizes, int n_in,
                              void* d_out, int out_size, void* d_ws, size_t ws_size,
                              hipStream_t stream)
{
    const float* vals   = (const float*)d_in[0];
    const int*   idxs   = (const int*)  d_in[1];
    const float* rand_u = (const float*)d_in[2];
    const float* kr     = (const float*)d_in[3];
    float*       out    = (float*)d_out;

    const int E  = in_sizes[0];       // 16,000,000
    const int NI = in_sizes[1];       // 32,000,000
    const int nv4 = E  / 4;           // 4,000,000 vec4 units
    const int ni4 = NI / 4;           // 8,000,000 vec4 units

    const int block   = 256;
    const int perBlk  = block * UNROLL;                 // 1024 units/block
    const int blocksV = (nv4 + perBlk - 1) / perBlk;    // 3907
    const int blocksI = (ni4 + perBlk - 1) / perBlk;    // 7813
    const int grid    = blocksV + blocksI;              // 11720

    SpAdjDropEdge_48541720379660_kernel<<<grid, block, 0, stream>>>(
        vals, idxs, rand_u, kr, out, nv4, ni4, blocksV);
}

// Round 5
// 84.836 us; speedup vs baseline: 1.0298x; 1.0298x over previous
//
#include <hip/hip_runtime.h>

typedef float  float4_t __attribute__((ext_vector_type(4)));
typedef int    int4_t   __attribute__((ext_vector_type(4)));

// Phase 1: new_vals = keep ? vals/kr : 0        (2:1 read:write, 192 MB)
__global__ void __launch_bounds__(256)
spade_vals_kernel(const float* __restrict__ vals,
                  const float* __restrict__ rand_u,
                  const float* __restrict__ keep_rate_p,
                  float*       __restrict__ out,
                  int nv4)
{
    const int i = blockIdx.x * blockDim.x + threadIdx.x;
    if (i >= nv4) return;
    const float kr = keep_rate_p[0];

    float4_t v = reinterpret_cast<const float4_t*>(vals)[i];
    float4_t r = reinterpret_cast<const float4_t*>(rand_u)[i];
    float4_t o;
#pragma unroll
    for (int j = 0; j < 4; ++j) {
        // reference: mask = floor(rand_u + keep_rate) != 0
        bool keep = (floorf(r[j] + kr) != 0.0f);
        o[j] = keep ? (v[j] / kr) : 0.0f;
    }
    reinterpret_cast<float4_t*>(out)[i] = o;
}

// Phase 2: out[E + j] = (float)idxs[j]          (1:1 read:write, 256 MB — copy shape)
__global__ void __launch_bounds__(256)
spade_idx_kernel(const int* __restrict__ idxs,
                 float*     __restrict__ outi,
                 int ni4)
{
    const int i = blockIdx.x * blockDim.x + threadIdx.x;
    if (i >= ni4) return;

    int4_t id = reinterpret_cast<const int4_t*>(idxs)[i];
    float4_t o;
#pragma unroll
    for (int j = 0; j < 4; ++j)
        o[j] = (float)id[j];   // node ids < 2^24 -> exact in f32
    reinterpret_cast<float4_t*>(outi)[i] = o;
}

extern "C" void kernel_launch(void* const* d_in, const int* in_sizes, int n_in,
                              void* d_out, int out_size, void* d_ws, size_t ws_size,
                              hipStream_t stream)
{
    const float* vals   = (const float*)d_in[0];
    const int*   idxs   = (const int*)  d_in[1];
    const float* rand_u = (const float*)d_in[2];
    const float* kr     = (const float*)d_in[3];
    float*       out    = (float*)d_out;

    const int E  = in_sizes[0];       // 16,000,000
    const int NI = in_sizes[1];       // 32,000,000
    const int nv4 = E  / 4;           // 4,000,000 vec4 units
    const int ni4 = NI / 4;           // 8,000,000 vec4 units

    const int block = 256;
    const int gridV = (nv4 + block - 1) / block;   // 15625
    const int gridI = (ni4 + block - 1) / block;   // 31250

    spade_vals_kernel<<<gridV, block, 0, stream>>>(vals, rand_u, kr, out, nv4);
    spade_idx_kernel <<<gridI, block, 0, stream>>>(idxs, out + (size_t)nv4 * 4, ni4);
}

// Round 6
// 83.017 us; speedup vs baseline: 1.0524x; 1.0219x over previous
//
#include <hip/hip_runtime.h>

typedef float  float4_t __attribute__((ext_vector_type(4)));
typedef int    int4_t   __attribute__((ext_vector_type(4)));

// Exact-cover elementwise streamer, one vec4 unit per thread (R3 structure),
// block=1024 to cut workgroup count 4x (dispatch-churn probe):
//   units [0, nv4)        : new_vals = keep ? vals/kr : 0
//   units [nv4, nv4+ni4)  : out[E + j] = (float)idxs[j]  (pass-through as f32)
__global__ void __launch_bounds__(1024)
SpAdjDropEdge_48541720379660_kernel(
    const float* __restrict__ vals,
    const int*   __restrict__ idxs,
    const float* __restrict__ rand_u,
    const float* __restrict__ keep_rate_p,
    float*       __restrict__ out,
    int nv4, int total)
{
    const int i = blockIdx.x * blockDim.x + threadIdx.x;
    if (i >= total) return;

    const float kr = keep_rate_p[0];

    if (i < nv4) {
        float4_t v = reinterpret_cast<const float4_t*>(vals)[i];
        float4_t r = reinterpret_cast<const float4_t*>(rand_u)[i];
        float4_t o;
#pragma unroll
        for (int j = 0; j < 4; ++j) {
            // reference: mask = floor(rand_u + keep_rate) != 0
            bool keep = (floorf(r[j] + kr) != 0.0f);
            o[j] = keep ? (v[j] / kr) : 0.0f;
        }
        reinterpret_cast<float4_t*>(out)[i] = o;
    } else {
        const int k = i - nv4;
        int4_t id = reinterpret_cast<const int4_t*>(idxs)[k];
        float4_t o;
#pragma unroll
        for (int j = 0; j < 4; ++j) {
            o[j] = (float)id[j];   // node ids < 2^24 -> exact in f32
        }
        reinterpret_cast<float4_t*>(out + (size_t)nv4 * 4)[k] = o;
    }
}

extern "C" void kernel_launch(void* const* d_in, const int* in_sizes, int n_in,
                              void* d_out, int out_size, void* d_ws, size_t ws_size,
                              hipStream_t stream)
{
    const float* vals   = (const float*)d_in[0];
    const int*   idxs   = (const int*)  d_in[1];
    const float* rand_u = (const float*)d_in[2];
    const float* kr     = (const float*)d_in[3];
    float*       out    = (float*)d_out;

    const int E  = in_sizes[0];       // 16,000,000
    const int NI = in_sizes[1];       // 32,000,000
    const int nv4   = E  / 4;         // 4,000,000 vec4 units
    const int ni4   = NI / 4;         // 8,000,000 vec4 units
    const int total = nv4 + ni4;      // 12,000,000 units

    const int block = 1024;
    const int grid  = (total + block - 1) / block;   // 11719 workgroups

    SpAdjDropEdge_48541720379660_kernel<<<grid, block, 0, stream>>>(
        vals, idxs, rand_u, kr, out, nv4, total);
}